// Round 7
// baseline (121.351 us; speedup 1.0000x reference)
//
#include <hip/hip_runtime.h>
#include <hip/hip_bf16.h>
#include <stdint.h>

#define S_TOK 3072
#define E_DIM 1280
#define H_NUM 20
#define D_HEAD 64
#define NSEG 16

typedef __attribute__((ext_vector_type(8))) short short8;
typedef __attribute__((ext_vector_type(4))) float f32x4;

__device__ __forceinline__ unsigned short f2bf(float f){
  union { float f; unsigned int i; } u; u.f = f;
  unsigned int r = u.i + 0x7FFFu + ((u.i >> 16) & 1u);
  return (unsigned short)(r >> 16);
}

__device__ __forceinline__ void gload_lds16(const void* g, void* l){
  __builtin_amdgcn_global_load_lds((__attribute__((address_space(1))) void*)(g),
                                   (__attribute__((address_space(3))) void*)(l), 16, 0, 0);
}

// ---------------- all f32 -> bf16 conversions in one launch ----------------
__global__ void cvt_all(const float* __restrict__ hs,
                        const float* __restrict__ w0, const float* __restrict__ w1,
                        const float* __restrict__ w2, const float* __restrict__ w3,
                        unsigned short* __restrict__ hsb,
                        unsigned short* __restrict__ dqkv, unsigned short* __restrict__ dob,
                        int nHS4, int nW4){
  int i = blockIdx.x * blockDim.x + threadIdx.x;
  const float* src;
  unsigned short* dst;
  size_t sj, dj;
  if (i < nHS4){
    src = hs; dst = hsb; sj = i; dj = i;
  } else {
    int t = i - nHS4;
    int w = t / nW4;
    if (w >= 4) return;
    int j = t - w * nW4;
    src = (w == 0) ? w0 : (w == 1) ? w1 : (w == 2) ? w2 : w3;
    sj = j;
    if (w < 3){ dst = dqkv; dj = (size_t)w * nW4 + j; }
    else      { dst = dob;  dj = j; }
  }
  float4 v = reinterpret_cast<const float4*>(src)[sj];
  ushort4 o;
  o.x = f2bf(v.x); o.y = f2bf(v.y); o.z = f2bf(v.z); o.w = f2bf(v.w);
  reinterpret_cast<ushort4*>(dst)[dj] = o;
}

// ---------------- 8-phase 256x256 GEMM: C = A[M,K] @ B[N,K]^T ----------------
// 8 waves (2M x 4N), wave-tile 128x64, BK=64 split into 2 half-tiles of
// 128 rows each, 2x double-buffered (128 KB LDS). Per phase: ds_read one
// quadrant's frags + issue ONE half-tile prefetch -> barrier -> lgkmcnt(0)
// -> 16 MFMA (setprio) -> [q3: vmcnt(2)] -> barrier. vmcnt never 0 mid-loop.
// Stage map (write-after-read safe): Ah0/Ah1/Bh1 of tile t+1 at t's q0/q1/q2
// (opposite buffer); Bh0 of tile t+2 at t's q3 (region last read at q2).
// MODE 0: QKV fused (N=3E): LDS-staged coalesced scatter to q/k/v [H][S][D]
// MODE 1: out proj (N=E): f32 out [S][E] + bias
template<int MODE>
__global__ __launch_bounds__(512, 2) void gemm256(
    const unsigned short* __restrict__ A,
    const unsigned short* __restrict__ Bp,
    const float* __restrict__ bias0,
    const float* __restrict__ bias1,
    unsigned short* __restrict__ Oq,
    unsigned short* __restrict__ Ok,
    unsigned short* __restrict__ Ov,
    float* __restrict__ Of,
    int M, int N, int K)
{
  // A: 2buf x 2half x [128][64] = 32768 shorts; B same at +32768. 128 KB.
  __shared__ __align__(16) unsigned short SH[65536];

  const int nbn = N >> 8;
  const int bm = blockIdx.x / nbn;
  const int bn = blockIdx.x % nbn;
  const int row0 = bm << 8;
  const int col0 = bn << 8;

  const int tid  = threadIdx.x;
  const int lane = tid & 63;
  const int w    = tid >> 6;
  const int wm   = w >> 2;        // 0..1  (M half)
  const int wn   = w & 3;         // 0..3  (N quarter)

  const f32x4 fz = {0.f, 0.f, 0.f, 0.f};
  f32x4 acc[8][4];
#pragma unroll
  for (int m = 0; m < 8; ++m)
#pragma unroll
    for (int n = 0; n < 4; ++n) acc[m][n] = fz;

  // staging: 1024 16B-slots per half-tile, 2 per thread.
  // slot s: r = s>>3 (row 0..127), p = s&7; holds k-chunk p^(r&7) (swizzle)
  const int sA = tid, sB = 512 + tid;
  const int r1 = sA >> 3, p1 = (sA & 7) ^ (r1 & 7);
  const int r2 = sB >> 3, p2 = (sB & 7) ^ (r2 & 7);
  const size_t go1 = (size_t)r1 * K + p1 * 8;
  const size_t go2 = (size_t)r2 * K + p2 * 8;
  const int lo1 = sA * 8, lo2 = sB * 8;

  auto stageA = [&](int t, int half){
    unsigned short* dst = SH + (((t & 1) * 2 + half) << 13);
    const unsigned short* g = A + (size_t)(row0 + half * 128) * K + (t << 6);
    gload_lds16(g + go1, dst + lo1);
    gload_lds16(g + go2, dst + lo2);
  };
  auto stageB = [&](int t, int half){
    unsigned short* dst = SH + 32768 + (((t & 1) * 2 + half) << 13);
    const unsigned short* g = Bp + (size_t)(col0 + half * 128) * K + (t << 6);
    gload_lds16(g + go1, dst + lo1);
    gload_lds16(g + go2, dst + lo2);
  };

  const int nk = K >> 6;            // 20
  // prologue: tile 0 fully + tile 1's Bh0; never drain below 2
  stageA(0, 0); stageA(0, 1); stageB(0, 0); stageB(0, 1); stageB(1, 0);
  asm volatile("s_waitcnt vmcnt(2)" ::: "memory");
  __builtin_amdgcn_s_barrier();

  short8 af[4][2];
  for (int t = 0; t < nk; ++t){
    const unsigned short* Ah = SH + (((t & 1) * 2 + wm) << 13);
    const unsigned short* Bh = SH + 32768 + (((t & 1) * 2 + (wn >> 1)) << 13);
#pragma unroll
    for (int q = 0; q < 4; ++q){
      const int mh = q >> 1, nh = q & 1;
      if (q == 0 || q == 2){
#pragma unroll
        for (int m = 0; m < 4; ++m){
          int ra = mh * 64 + m * 16 + (lane & 15);
#pragma unroll
          for (int kk = 0; kk < 2; ++kk){
            int slot = kk * 4 + (lane >> 4);
            af[m][kk] = *reinterpret_cast<const short8*>(&Ah[ra * 64 + ((slot ^ (ra & 7))) * 8]);
          }
        }
      }
      short8 bf[2][2];
#pragma unroll
      for (int n = 0; n < 2; ++n){
        int rb = (wn & 1) * 64 + (nh * 2 + n) * 16 + (lane & 15);
#pragma unroll
        for (int kk = 0; kk < 2; ++kk){
          int slot = kk * 4 + (lane >> 4);
          bf[n][kk] = *reinterpret_cast<const short8*>(&Bh[rb * 64 + ((slot ^ (rb & 7))) * 8]);
        }
      }
      // one half-tile prefetch per phase
      if (q == 0){ if (t + 1 < nk) stageA(t + 1, 0); }
      else if (q == 1){ if (t + 1 < nk) stageA(t + 1, 1); }
      else if (q == 2){ if (t + 1 < nk) stageB(t + 1, 1); }
      else            { if (t + 2 < nk) stageB(t + 2, 0); }

      __builtin_amdgcn_s_barrier();
      asm volatile("s_waitcnt lgkmcnt(0)" ::: "memory");
      __builtin_amdgcn_sched_barrier(0);
      __builtin_amdgcn_s_setprio(1);
#pragma unroll
      for (int kk = 0; kk < 2; ++kk)
#pragma unroll
        for (int m = 0; m < 4; ++m)
#pragma unroll
          for (int n = 0; n < 2; ++n)
            acc[mh * 4 + m][nh * 2 + n] =
                __builtin_amdgcn_mfma_f32_16x16x32_bf16(af[m][kk], bf[n][kk],
                                                        acc[mh * 4 + m][nh * 2 + n], 0, 0, 0);
      __builtin_amdgcn_s_setprio(0);
      if (q == 3) asm volatile("s_waitcnt vmcnt(2)" ::: "memory");
      __builtin_amdgcn_s_barrier();
    }
  }
  __syncthreads();   // drain before epilogue reuses SH

  if (MODE == 0){
    // coalesced scatter epilogue: two 128-row phases staged in LDS
    unsigned short* Cs = SH;
    const int CSTR = 264;                  // 128 x 264 = 33792 shorts <= 65536
    const int mat = col0 / E_DIM;          // tile-uniform (1280 % 256 == 0)
    const int cc0 = col0 - mat * E_DIM;
    unsigned short* dst = (mat == 0) ? Oq : ((mat == 1) ? Ok : Ov);
    float bb[4];
#pragma unroll
    for (int n = 0; n < 4; ++n){
      int cc = cc0 + wn * 64 + n * 16 + (lane & 15);
      bb[n] = (mat == 0) ? bias0[cc] : (mat == 2 ? bias1[cc] : 0.0f);
    }
#pragma unroll
    for (int ph = 0; ph < 2; ++ph){
      if (wm == ph){
#pragma unroll
        for (int m = 0; m < 8; ++m)
#pragma unroll
          for (int n = 0; n < 4; ++n)
#pragma unroll
            for (int j = 0; j < 4; ++j){
              int rr = m * 16 + (lane >> 4) * 4 + j;      // 0..127
              int c  = wn * 64 + n * 16 + (lane & 15);    // 0..255
              Cs[rr * CSTR + c] = f2bf(acc[m][n][j] + bb[n]);
            }
      }
      __syncthreads();
#pragma unroll
      for (int i = 0; i < 8; ++i){
        int tk  = i * 512 + tid;        // 4096 tasks = 4 head-panels x 128r x 8sl
        int p   = tk >> 10;
        int idx = tk & 1023;
        int rr  = idx >> 3, sq = idx & 7;
        short8 vv = *reinterpret_cast<const short8*>(&Cs[rr * CSTR + p * 64 + sq * 8]);
        int gr = row0 + ph * 128 + rr;
        int hh = (cc0 >> 6) + p;
        *reinterpret_cast<short8*>(&dst[((size_t)hh * S_TOK + gr) * D_HEAD + sq * 8]) = vv;
      }
      __syncthreads();
    }
  } else {
#pragma unroll
    for (int m = 0; m < 8; ++m)
#pragma unroll
      for (int n = 0; n < 4; ++n){
        int c = col0 + wn * 64 + n * 16 + (lane & 15);
        float b = bias0[c];
#pragma unroll
        for (int j = 0; j < 4; ++j){
          int r = row0 + wm * 128 + m * 16 + (lane >> 4) * 4 + j;
          Of[(size_t)r * E_DIM + c] = acc[m][n][j] + b;
        }
      }
  }
}

// ---------------- block-diagonal attention ----------------
// grid = H*NSEG*3 blocks of 256 threads (4 waves x 16 Q-rows = 64 rows/block).
#define VSTR 200
#define PSTR 72
__global__ __launch_bounds__(256, 3) void attn_kernel(
    const unsigned short* __restrict__ Q,
    const unsigned short* __restrict__ Kb,
    const unsigned short* __restrict__ V,
    const int* __restrict__ cu,
    unsigned short* __restrict__ O)
{
  __shared__ __align__(16) unsigned short Vt[64*VSTR];     // [d][k-row]
  __shared__ __align__(16) unsigned short Pw[4][16][PSTR]; // per-wave scratch

  const int bid  = blockIdx.x;
  const int unit = bid / 3;
  const int third= bid - unit*3;
  const int h    = unit >> 4;
  const int seg  = unit & 15;
  const int s0   = cu[seg];
  const int L    = cu[seg + 1] - s0;
  if (L <= 0) return;

  const int tid  = threadIdx.x;
  const int lane = tid & 63;
  const int w    = tid >> 6;
  const int row0g = third*64 + w*16;

  const unsigned short* qh = Q  + (size_t)h * S_TOK * D_HEAD;
  const unsigned short* kh = Kb + (size_t)h * S_TOK * D_HEAD;
  const unsigned short* vh = V  + (size_t)h * S_TOK * D_HEAD;

#pragma unroll
  for (int i = 0; i < 6; ++i){
    int task = i*256 + tid;            // 1536 tasks = 192 rows x 8 d-groups
    int sr   = task % 192;
    int grp  = task / 192;
    int svr  = s0 + (sr < L ? sr : L - 1);
    short8 vv = *reinterpret_cast<const short8*>(vh + (size_t)svr*64 + grp*8);
#pragma unroll
    for (int j = 0; j < 8; ++j) Vt[(grp*8 + j)*VSTR + sr] = (unsigned short)vv[j];
  }

  short8 qf[2];
#pragma unroll
  for (int kk = 0; kk < 2; ++kk){
    int r  = row0g + (lane & 15);
    int sr = s0 + (r < L ? r : L - 1);
    qf[kk] = *reinterpret_cast<const short8*>(qh + (size_t)sr*64 + kk*32 + (lane >> 4)*8);
  }

  __syncthreads();

  const f32x4 fz = {0.f, 0.f, 0.f, 0.f};
  const float SCL = 0.125f * 1.44269504088896f;

  f32x4 sacc[12];
#pragma unroll
  for (int nt = 0; nt < 12; ++nt) sacc[nt] = fz;

#pragma unroll
  for (int nt = 0; nt < 12; ++nt){
    int rb = nt*16 + (lane & 15);
    int sr = s0 + (rb < L ? rb : L - 1);
    const unsigned short* kr = kh + (size_t)sr*64 + (lane >> 4)*8;
    short8 kf0 = *reinterpret_cast<const short8*>(kr);
    short8 kf1 = *reinterpret_cast<const short8*>(kr + 32);
    sacc[nt] = __builtin_amdgcn_mfma_f32_16x16x32_bf16(qf[0], kf0, sacc[nt], 0, 0, 0);
    sacc[nt] = __builtin_amdgcn_mfma_f32_16x16x32_bf16(qf[1], kf1, sacc[nt], 0, 0, 0);
  }

  float rinv[4];
#pragma unroll
  for (int j = 0; j < 4; ++j){
    float mx = -1e30f;
#pragma unroll
    for (int nt = 0; nt < 12; ++nt){
      int c = nt*16 + (lane & 15);
      float vv = (c < L) ? sacc[nt][j] : -1e30f;
      sacc[nt][j] = vv;
      mx = fmaxf(mx, vv);
    }
    mx = fmaxf(mx, __shfl_xor(mx, 1, 64));
    mx = fmaxf(mx, __shfl_xor(mx, 2, 64));
    mx = fmaxf(mx, __shfl_xor(mx, 4, 64));
    mx = fmaxf(mx, __shfl_xor(mx, 8, 64));
    float sum = 0.f;
#pragma unroll
    for (int nt = 0; nt < 12; ++nt){
      float pp = exp2f((sacc[nt][j] - mx) * SCL);
      sacc[nt][j] = pp;
      sum += pp;
    }
    sum += __shfl_xor(sum, 1, 64);
    sum += __shfl_xor(sum, 2, 64);
    sum += __shfl_xor(sum, 4, 64);
    sum += __shfl_xor(sum, 8, 64);
    rinv[j] = 1.0f / sum;
  }

  f32x4 oacc[4];
#pragma unroll
  for (int nt = 0; nt < 4; ++nt) oacc[nt] = fz;

#pragma unroll
  for (int kk = 0; kk < 6; ++kk){
#pragma unroll
    for (int ntl = 0; ntl < 2; ++ntl){
      int nt = kk*2 + ntl;
#pragma unroll
      for (int j = 0; j < 4; ++j)
        Pw[w][(lane >> 4)*4 + j][ntl*16 + (lane & 15)] = f2bf(sacc[nt][j]);
    }
    short8 pf = *reinterpret_cast<const short8*>(&Pw[w][lane & 15][(lane >> 4)*8]);
#pragma unroll
    for (int nt4 = 0; nt4 < 4; ++nt4){
      int dcol = nt4*16 + (lane & 15);
      short8 vf = *reinterpret_cast<const short8*>(&Vt[dcol*VSTR + kk*32 + (lane >> 4)*8]);
      oacc[nt4] = __builtin_amdgcn_mfma_f32_16x16x32_bf16(pf, vf, oacc[nt4], 0, 0, 0);
    }
  }

#pragma unroll
  for (int nt4 = 0; nt4 < 4; ++nt4)
#pragma unroll
    for (int j = 0; j < 4; ++j)
      Pw[w][(lane >> 4)*4 + j][nt4*16 + (lane & 15)] = f2bf(oacc[nt4][j] * rinv[j]);

  {
    int r = lane >> 2;
    int gr = row0g + r;
    if (gr < L){
#pragma unroll
      for (int part = 0; part < 2; ++part){
        int c0 = (lane & 3)*16 + part*8;
        short8 vv = *reinterpret_cast<const short8*>(&Pw[w][r][c0]);
        *reinterpret_cast<short8*>(&O[(size_t)(s0 + gr) * E_DIM + h*64 + c0]) = vv;
      }
    }
  }
}

// ---------------- host launch ----------------
extern "C" void kernel_launch(void* const* d_in, const int* in_sizes, int n_in,
                              void* d_out, int out_size, void* d_ws, size_t ws_size,
                              hipStream_t stream)
{
  const float* hs = (const float*)d_in[0];
  const float* Wq = (const float*)d_in[1];
  const float* bq = (const float*)d_in[2];
  const float* Wk = (const float*)d_in[3];
  const float* Wv = (const float*)d_in[4];
  const float* bv = (const float*)d_in[5];
  const float* Wo = (const float*)d_in[6];
  const float* bo = (const float*)d_in[7];
  const int*   cu = (const int*)d_in[8];
  float* out = (float*)d_out;

  unsigned short* p = (unsigned short*)d_ws;
  unsigned short* hsb  = p; p += (size_t)S_TOK * E_DIM;
  unsigned short* wqkv = p; p += (size_t)3 * E_DIM * E_DIM;
  unsigned short* wob  = p; p += (size_t)E_DIM * E_DIM;
  unsigned short* qb   = p; p += (size_t)S_TOK * E_DIM;
  unsigned short* kb   = p; p += (size_t)S_TOK * E_DIM;
  unsigned short* vb   = p; p += (size_t)S_TOK * E_DIM;
  unsigned short* aob  = p; p += (size_t)S_TOK * E_DIM;

  const int nHS4 = S_TOK * E_DIM / 4;
  const int nW4  = E_DIM * E_DIM / 4;
  const int nCvt = nHS4 + 4 * nW4;
  cvt_all<<<(nCvt + 255) / 256, 256, 0, stream>>>(hs, Wq, Wk, Wv, Wo, hsb, wqkv, wob, nHS4, nW4);

  gemm256<0><<<(S_TOK/256) * (3*E_DIM/256), 512, 0, stream>>>(
      hsb, wqkv, bq, bv, qb, kb, vb, nullptr, S_TOK, 3*E_DIM, E_DIM);

  attn_kernel<<<H_NUM * NSEG * 3, 256, 0, stream>>>(qb, kb, vb, cu, aob);

  gemm256<1><<<(S_TOK/256) * (E_DIM/256), 512, 0, stream>>>(
      aob, wob, bo, nullptr, nullptr, nullptr, nullptr, out, S_TOK, E_DIM, E_DIM);
}

// Round 8
// 98.177 us; speedup vs baseline: 1.2360x; 1.2360x over previous
//
#include <hip/hip_runtime.h>
#include <hip/hip_bf16.h>
#include <stdint.h>

#define S_TOK 3072
#define E_DIM 1280
#define H_NUM 20
#define D_HEAD 64
#define NSEG 16

typedef __attribute__((ext_vector_type(8))) short short8;
typedef __attribute__((ext_vector_type(4))) float f32x4;

__device__ __forceinline__ unsigned short f2bf(float f){
  union { float f; unsigned int i; } u; u.f = f;
  unsigned int r = u.i + 0x7FFFu + ((u.i >> 16) & 1u);
  return (unsigned short)(r >> 16);
}

__device__ __forceinline__ void gload_lds16(const void* g, void* l){
  __builtin_amdgcn_global_load_lds((__attribute__((address_space(1))) void*)(g),
                                   (__attribute__((address_space(3))) void*)(l), 16, 0, 0);
}

// ---------------- all f32 -> bf16 conversions in one launch ----------------
__global__ void cvt_all(const float* __restrict__ hs,
                        const float* __restrict__ w0, const float* __restrict__ w1,
                        const float* __restrict__ w2, const float* __restrict__ w3,
                        unsigned short* __restrict__ hsb,
                        unsigned short* __restrict__ dqkv, unsigned short* __restrict__ dob,
                        int nHS4, int nW4){
  int i = blockIdx.x * blockDim.x + threadIdx.x;
  const float* src;
  unsigned short* dst;
  size_t sj, dj;
  if (i < nHS4){
    src = hs; dst = hsb; sj = i; dj = i;
  } else {
    int t = i - nHS4;
    int w = t / nW4;
    if (w >= 4) return;
    int j = t - w * nW4;
    src = (w == 0) ? w0 : (w == 1) ? w1 : (w == 2) ? w2 : w3;
    sj = j;
    if (w < 3){ dst = dqkv; dj = (size_t)w * nW4 + j; }
    else      { dst = dob;  dj = j; }
  }
  float4 v = reinterpret_cast<const float4*>(src)[sj];
  ushort4 o;
  o.x = f2bf(v.x); o.y = f2bf(v.y); o.z = f2bf(v.z); o.w = f2bf(v.w);
  reinterpret_cast<ushort4*>(dst)[dj] = o;
}

// ---------------- pipelined GEMM: C = A[M,K] @ B[N,K]^T (bf16, f32 acc) -------
// BK=32, ring-4 tile slots, stage tile t+2 during tile t (2-tile latency
// cover), ONE vmcnt+barrier per tile. Entry of tile t: vmcnt(4) guarantees
// tile t complete (only t+1's 4 loads may remain in flight); slot (t+2)&3 was
// last read at tile t-2 (two barriers ago) -> write-after-read safe.
// Swizzle (r5-verified 0-conflict): phys 16B-slot p of row r holds k-chunk
// p ^ ((r>>1)&3).
// MODE 0: BM=BN=256, 8 waves (2x4), wave-tile 128x64, scatter q/k/v bf16.
// MODE 1: BM=BN=128, 4 waves (2x2), wave-tile 64x64, f32 out + bias.
template<int MODE, int BLOCK>
__global__ __launch_bounds__(BLOCK, 2) void gemm_pipe(
    const unsigned short* __restrict__ A,
    const unsigned short* __restrict__ Bp,
    const float* __restrict__ bias0,
    const float* __restrict__ bias1,
    unsigned short* __restrict__ Oq,
    unsigned short* __restrict__ Ok,
    unsigned short* __restrict__ Ov,
    float* __restrict__ Of,
    int M, int N, int K)
{
  constexpr int BM = (MODE == 0) ? 256 : 128;
  constexpr int BN = BM;
  constexpr int WN = (MODE == 0) ? 4 : 2;
  constexpr int WM = (BLOCK / 64) / WN;
  constexpr int MR = BM / WM / 16;      // 8 / 4
  constexpr int NR = BN / WN / 16;      // 4 / 4
  constexpr int SLOTSZ = (BM + BN) * 32;  // shorts per ring slot

  __shared__ __align__(16) unsigned short SH[4 * SLOTSZ];

  const int nbn = N >> (MODE == 0 ? 8 : 7);
  // supertile remap (4bm x 5bn chunks) for L2 locality; bijective since
  // nbm%4==0 and nbn%5==0 for both shapes here.
  const int sgn = nbn / 5;
  const int st = blockIdx.x / 20, ii = blockIdx.x % 20;
  const int bm = (st / sgn) * 4 + ii / 5;
  const int bn = (st % sgn) * 5 + ii % 5;
  const int row0 = bm * BM;
  const int col0 = bn * BN;

  const int tid  = threadIdx.x;
  const int lane = tid & 63;
  const int w    = tid >> 6;
  const int wm   = (MODE == 0) ? (w >> 2) : (w >> 1);
  const int wn   = (MODE == 0) ? (w & 3) : (w & 1);

  const f32x4 fz = {0.f, 0.f, 0.f, 0.f};
  f32x4 acc[MR][NR];
#pragma unroll
  for (int m = 0; m < MR; ++m)
#pragma unroll
    for (int n = 0; n < NR; ++n) acc[m][n] = fz;

  // per-thread staging slots (4 each)
  auto stage = [&](int slot, int t){
    unsigned short* base = SH + slot * SLOTSZ;
    const int k0 = t << 5;
#pragma unroll
    for (int i = 0; i < 4; ++i){
      int s = i * BLOCK + tid;
      int r = s >> 2, p = s & 3;
      int ks = p ^ ((r >> 1) & 3);
      const unsigned short* g = (r < BM)
          ? A  + (size_t)(row0 + r) * K + k0 + ks * 8
          : Bp + (size_t)(col0 + (r - BM)) * K + k0 + ks * 8;
      gload_lds16(g, base + s * 8);
    }
  };

  const int nk = K >> 5;               // 40
  stage(0, 0);
  stage(1, 1);
  for (int t = 0; t < nk; ++t){
    if (t == nk - 1) asm volatile("s_waitcnt vmcnt(0)" ::: "memory");
    else             asm volatile("s_waitcnt vmcnt(4)" ::: "memory");
    __builtin_amdgcn_s_barrier();
    if (t + 2 < nk) stage((t + 2) & 3, t + 2);

    const unsigned short* As = SH + (t & 3) * SLOTSZ;
    const unsigned short* Bs = As + BM * 32;
    short8 af[MR], bf[NR];
#pragma unroll
    for (int n = 0; n < NR; ++n){
      int rb = wn * (BN / WN) + n * 16 + (lane & 15);
      bf[n] = *reinterpret_cast<const short8*>(&Bs[rb * 32 + (((lane >> 4) ^ ((rb >> 1) & 3))) * 8]);
    }
#pragma unroll
    for (int m = 0; m < MR; ++m){
      int ra = wm * (BM / WM) + m * 16 + (lane & 15);
      af[m] = *reinterpret_cast<const short8*>(&As[ra * 32 + (((lane >> 4) ^ ((ra >> 1) & 3))) * 8]);
    }
    __builtin_amdgcn_s_setprio(1);
#pragma unroll
    for (int m = 0; m < MR; ++m)
#pragma unroll
      for (int n = 0; n < NR; ++n)
        acc[m][n] = __builtin_amdgcn_mfma_f32_16x16x32_bf16(af[m], bf[n], acc[m][n], 0, 0, 0);
    __builtin_amdgcn_s_setprio(0);
  }
  __syncthreads();   // drain all LDS reads before epilogue reuses SH

  if (MODE == 0){
    // coalesced scatter epilogue: two 128-row phases staged in LDS
    unsigned short* Cs = SH;
    const int CSTR = 264;                  // 128 x 264 = 33792 shorts
    const int mat = col0 / E_DIM;          // tile-uniform (1280 % 256 == 0)
    const int cc0 = col0 - mat * E_DIM;
    unsigned short* dst = (mat == 0) ? Oq : ((mat == 1) ? Ok : Ov);
    float bb[NR];
#pragma unroll
    for (int n = 0; n < NR; ++n){
      int cc = cc0 + wn * 64 + n * 16 + (lane & 15);
      bb[n] = (mat == 0) ? bias0[cc] : (mat == 2 ? bias1[cc] : 0.0f);
    }
#pragma unroll
    for (int ph = 0; ph < 2; ++ph){
      if (wm == ph){
#pragma unroll
        for (int m = 0; m < MR; ++m)
#pragma unroll
          for (int n = 0; n < NR; ++n)
#pragma unroll
            for (int j = 0; j < 4; ++j){
              int rr = m * 16 + (lane >> 4) * 4 + j;      // 0..127
              int c  = wn * 64 + n * 16 + (lane & 15);    // 0..255
              Cs[rr * CSTR + c] = f2bf(acc[m][n][j] + bb[n]);
            }
      }
      __syncthreads();
#pragma unroll
      for (int i = 0; i < 8; ++i){
        int tk  = i * 512 + tid;        // 4096 tasks = 4 head-panels x 128r x 8sl
        int p   = tk >> 10;
        int idx = tk & 1023;
        int rr  = idx >> 3, sq = idx & 7;
        short8 vv = *reinterpret_cast<const short8*>(&Cs[rr * CSTR + p * 64 + sq * 8]);
        int gr = row0 + ph * 128 + rr;
        int hh = (cc0 >> 6) + p;
        *reinterpret_cast<short8*>(&dst[((size_t)hh * S_TOK + gr) * D_HEAD + sq * 8]) = vv;
      }
      __syncthreads();
    }
  } else {
#pragma unroll
    for (int m = 0; m < MR; ++m)
#pragma unroll
      for (int n = 0; n < NR; ++n){
        int c = col0 + wn * 64 + n * 16 + (lane & 15);
        float b = bias0[c];
#pragma unroll
        for (int j = 0; j < 4; ++j){
          int r = row0 + wm * 64 + m * 16 + (lane >> 4) * 4 + j;
          Of[(size_t)r * E_DIM + c] = acc[m][n][j] + b;
        }
      }
  }
}

// ---------------- block-diagonal attention ----------------
// grid = H*NSEG*3 blocks of 256 threads (4 waves x 16 Q-rows = 64 rows/block).
#define VSTR 200
#define PSTR 72
__global__ __launch_bounds__(256, 3) void attn_kernel(
    const unsigned short* __restrict__ Q,
    const unsigned short* __restrict__ Kb,
    const unsigned short* __restrict__ V,
    const int* __restrict__ cu,
    unsigned short* __restrict__ O)
{
  __shared__ __align__(16) unsigned short Vt[64*VSTR];     // [d][k-row]
  __shared__ __align__(16) unsigned short Pw[4][16][PSTR]; // per-wave scratch

  const int bid  = blockIdx.x;
  const int unit = bid / 3;
  const int third= bid - unit*3;
  const int h    = unit >> 4;
  const int seg  = unit & 15;
  const int s0   = cu[seg];
  const int L    = cu[seg + 1] - s0;
  if (L <= 0) return;

  const int tid  = threadIdx.x;
  const int lane = tid & 63;
  const int w    = tid >> 6;
  const int row0g = third*64 + w*16;

  const unsigned short* qh = Q  + (size_t)h * S_TOK * D_HEAD;
  const unsigned short* kh = Kb + (size_t)h * S_TOK * D_HEAD;
  const unsigned short* vh = V  + (size_t)h * S_TOK * D_HEAD;

#pragma unroll
  for (int i = 0; i < 6; ++i){
    int task = i*256 + tid;            // 1536 tasks = 192 rows x 8 d-groups
    int sr   = task % 192;
    int grp  = task / 192;
    int svr  = s0 + (sr < L ? sr : L - 1);
    short8 vv = *reinterpret_cast<const short8*>(vh + (size_t)svr*64 + grp*8);
#pragma unroll
    for (int j = 0; j < 8; ++j) Vt[(grp*8 + j)*VSTR + sr] = (unsigned short)vv[j];
  }

  short8 qf[2];
#pragma unroll
  for (int kk = 0; kk < 2; ++kk){
    int r  = row0g + (lane & 15);
    int sr = s0 + (r < L ? r : L - 1);
    qf[kk] = *reinterpret_cast<const short8*>(qh + (size_t)sr*64 + kk*32 + (lane >> 4)*8);
  }

  __syncthreads();

  const f32x4 fz = {0.f, 0.f, 0.f, 0.f};
  const float SCL = 0.125f * 1.44269504088896f;

  f32x4 sacc[12];
#pragma unroll
  for (int nt = 0; nt < 12; ++nt) sacc[nt] = fz;

#pragma unroll
  for (int nt = 0; nt < 12; ++nt){
    int rb = nt*16 + (lane & 15);
    int sr = s0 + (rb < L ? rb : L - 1);
    const unsigned short* kr = kh + (size_t)sr*64 + (lane >> 4)*8;
    short8 kf0 = *reinterpret_cast<const short8*>(kr);
    short8 kf1 = *reinterpret_cast<const short8*>(kr + 32);
    sacc[nt] = __builtin_amdgcn_mfma_f32_16x16x32_bf16(qf[0], kf0, sacc[nt], 0, 0, 0);
    sacc[nt] = __builtin_amdgcn_mfma_f32_16x16x32_bf16(qf[1], kf1, sacc[nt], 0, 0, 0);
  }

  float rinv[4];
#pragma unroll
  for (int j = 0; j < 4; ++j){
    float mx = -1e30f;
#pragma unroll
    for (int nt = 0; nt < 12; ++nt){
      int c = nt*16 + (lane & 15);
      float vv = (c < L) ? sacc[nt][j] : -1e30f;
      sacc[nt][j] = vv;
      mx = fmaxf(mx, vv);
    }
    mx = fmaxf(mx, __shfl_xor(mx, 1, 64));
    mx = fmaxf(mx, __shfl_xor(mx, 2, 64));
    mx = fmaxf(mx, __shfl_xor(mx, 4, 64));
    mx = fmaxf(mx, __shfl_xor(mx, 8, 64));
    float sum = 0.f;
#pragma unroll
    for (int nt = 0; nt < 12; ++nt){
      float pp = exp2f((sacc[nt][j] - mx) * SCL);
      sacc[nt][j] = pp;
      sum += pp;
    }
    sum += __shfl_xor(sum, 1, 64);
    sum += __shfl_xor(sum, 2, 64);
    sum += __shfl_xor(sum, 4, 64);
    sum += __shfl_xor(sum, 8, 64);
    rinv[j] = 1.0f / sum;
  }

  f32x4 oacc[4];
#pragma unroll
  for (int nt = 0; nt < 4; ++nt) oacc[nt] = fz;

#pragma unroll
  for (int kk = 0; kk < 6; ++kk){
#pragma unroll
    for (int ntl = 0; ntl < 2; ++ntl){
      int nt = kk*2 + ntl;
#pragma unroll
      for (int j = 0; j < 4; ++j)
        Pw[w][(lane >> 4)*4 + j][ntl*16 + (lane & 15)] = f2bf(sacc[nt][j]);
    }
    short8 pf = *reinterpret_cast<const short8*>(&Pw[w][lane & 15][(lane >> 4)*8]);
#pragma unroll
    for (int nt4 = 0; nt4 < 4; ++nt4){
      int dcol = nt4*16 + (lane & 15);
      short8 vf = *reinterpret_cast<const short8*>(&Vt[dcol*VSTR + kk*32 + (lane >> 4)*8]);
      oacc[nt4] = __builtin_amdgcn_mfma_f32_16x16x32_bf16(pf, vf, oacc[nt4], 0, 0, 0);
    }
  }

#pragma unroll
  for (int nt4 = 0; nt4 < 4; ++nt4)
#pragma unroll
    for (int j = 0; j < 4; ++j)
      Pw[w][(lane >> 4)*4 + j][nt4*16 + (lane & 15)] = f2bf(oacc[nt4][j] * rinv[j]);

  {
    int r = lane >> 2;
    int gr = row0g + r;
    if (gr < L){
#pragma unroll
      for (int part = 0; part < 2; ++part){
        int c0 = (lane & 3)*16 + part*8;
        short8 vv = *reinterpret_cast<const short8*>(&Pw[w][r][c0]);
        *reinterpret_cast<short8*>(&O[(size_t)(s0 + gr) * E_DIM + h*64 + c0]) = vv;
      }
    }
  }
}

// ---------------- host launch ----------------
extern "C" void kernel_launch(void* const* d_in, const int* in_sizes, int n_in,
                              void* d_out, int out_size, void* d_ws, size_t ws_size,
                              hipStream_t stream)
{
  const float* hs = (const float*)d_in[0];
  const float* Wq = (const float*)d_in[1];
  const float* bq = (const float*)d_in[2];
  const float* Wk = (const float*)d_in[3];
  const float* Wv = (const float*)d_in[4];
  const float* bv = (const float*)d_in[5];
  const float* Wo = (const float*)d_in[6];
  const float* bo = (const float*)d_in[7];
  const int*   cu = (const int*)d_in[8];
  float* out = (float*)d_out;

  unsigned short* p = (unsigned short*)d_ws;
  unsigned short* hsb  = p; p += (size_t)S_TOK * E_DIM;
  unsigned short* wqkv = p; p += (size_t)3 * E_DIM * E_DIM;
  unsigned short* wob  = p; p += (size_t)E_DIM * E_DIM;
  unsigned short* qb   = p; p += (size_t)S_TOK * E_DIM;
  unsigned short* kb   = p; p += (size_t)S_TOK * E_DIM;
  unsigned short* vb   = p; p += (size_t)S_TOK * E_DIM;
  unsigned short* aob  = p; p += (size_t)S_TOK * E_DIM;

  const int nHS4 = S_TOK * E_DIM / 4;
  const int nW4  = E_DIM * E_DIM / 4;
  const int nCvt = nHS4 + 4 * nW4;
  cvt_all<<<(nCvt + 255) / 256, 256, 0, stream>>>(hs, Wq, Wk, Wv, Wo, hsb, wqkv, wob, nHS4, nW4);

  // QKV: 12 x 15 = 180 blocks of 512
  gemm_pipe<0, 512><<<(S_TOK/256) * (3*E_DIM/256), 512, 0, stream>>>(
      hsb, wqkv, bq, bv, qb, kb, vb, nullptr, S_TOK, 3*E_DIM, E_DIM);

  attn_kernel<<<H_NUM * NSEG * 3, 256, 0, stream>>>(qb, kb, vb, cu, aob);

  // out-proj: 24 x 10 = 240 blocks of 256
  gemm_pipe<1, 256><<<(S_TOK/128) * (E_DIM/128), 256, 0, stream>>>(
      aob, wob, bo, nullptr, nullptr, nullptr, nullptr, out, S_TOK, E_DIM, E_DIM);
}